// Round 12
// baseline (3356.716 us; speedup 1.0000x reference)
//
#include <hip/hip_runtime.h>
#include <hip/hip_fp16.h>
#include <hip/hip_cooperative_groups.h>

namespace cg = cooperative_groups;

// LightGCN 3-layer propagation, fp16 ego intermediates.
// Round 18: retry of the grid-synchronized dst-window gather, failure-
// proofed. Round 17's coop kernel almost certainly never ran (unchecked
// hipLaunchCooperativeKernel return; absmax == max|ref| == zero output)
// and/or overflowed the workspace (76.7MB > verified 74.3MB).
//  (1) coop launch is ERROR-CHECKED; on failure, falls back to the
//      verified 3-launch gather (round-13 structure, rowPtrW stride-5).
//  (2) footprint cut to ~68.7MB: pairs u64 -> u32 ([norm14][dst:18],
//      fixed-point norm, err <= 3e-5 vs 0.405 tolerance) — also halves
//      pairs traffic in every gather.
//  (3) __threadfence() before layer-boundary grid.sync() (cross-XCD L2
//      visibility, G16).
// Thesis unchanged: the 75us/launch gather is latency*concurrency-bound
// on random 128B rows; enforcing a chip-wide 4MB dst-window sweep makes
// row reads L2/L3-resident and lifts the request rate.

#define NUM_USERS 100000
#define NUM_ITEMS 50000
#define EMB_DIM   64
#define N_EDGES   2000000
#define N_NODES   (NUM_USERS + NUM_ITEMS)          // 150000
#define NODE_FLOATS (N_NODES * EMB_DIM)            // 9,600,000
#define NODE_F4     (NODE_FLOATS / 4)              // 2,400,000

#define NBUCKET  512
#define NPB      293        // nodes per bucket; 512*293 = 150016 >= 150000
#define NPART    8          // reservation partitions (XCD heuristic)
#define NCNT     (NBUCKET * NPART)                  // 4096
#define BT       512        // threads in bucket passes
#define VPT      8          // edges per thread in bucket passes
#define TILE     (BT * VPT)                         // 4096
#define NTILE    ((N_EDGES + TILE - 1) / TILE)      // 489
#define INITB    1024       // init-role blocks in the fused kernel

#define NQ       5          // dst windows: dst>>15 in 0..4 (4MB of rows)
#define NBIN     (NPB * NQ) // 1465 sort bins per bucket
#define NBIN2    2048       // padded scan width

#define COOP_BLOCKS 1024    // 4 blocks/CU co-resident
#define NPW         40      // nodes per wave (4096 waves * 40 >= 150000)
#define NGRP        5       // 5 groups of 8 node slots (8 chains in flight)

#define NORM_SCALE 16383.0f

typedef unsigned int uint;
typedef unsigned short ushort;
typedef unsigned long long u64;

__device__ __forceinline__ float2 h2f2(uint u) {
    __half2 h = *reinterpret_cast<const __half2*>(&u);
    return __half22float2(h);
}
__device__ __forceinline__ uint f2h2(float a, float b) {
    __half2 h = __floats2half2_rn(a, b);
    return *reinterpret_cast<uint*>(&h);
}
__device__ __forceinline__ float decw(uint p) {
    return (float)(p >> 18) * (1.0f / NORM_SCALE);
}

// ---------- fused: egoA(fp16) = concat(user,item)  +  bucket histogram ----
__global__ __launch_bounds__(BT) void init_and_hist(
        const float4* __restrict__ user,
        const float4* __restrict__ item,
        uint2* __restrict__ egoA,
        const int* __restrict__ src,
        int* __restrict__ bucketCount) {
    int t = threadIdx.x;
    if (blockIdx.x < NTILE) {
        __shared__ int cnt[NBUCKET];
        int part = blockIdx.x & (NPART - 1);
        cnt[t] = 0;
        __syncthreads();
        int base = blockIdx.x * TILE + t;
        #pragma unroll
        for (int k = 0; k < VPT; ++k) {
            int e = base + k * BT;
            if (e < N_EDGES) atomicAdd(&cnt[src[e] / NPB], 1);
        }
        __syncthreads();
        int c = cnt[t];
        if (c) atomicAdd(&bucketCount[t * NPART + part], c);
    } else {
        const int n_user4 = NUM_USERS * EMB_DIM / 4;
        int bid = blockIdx.x - NTILE;
        for (int i = bid * BT + t; i < NODE_F4; i += INITB * BT) {
            float4 v = (i < n_user4) ? user[i] : item[i - n_user4];
            egoA[i] = make_uint2(f2h2(v.x, v.y), f2h2(v.z, v.w));
        }
    }
}

// ---------- scan over 4096 (bucket,part) counters (1 block, 1024 thr) ----------
__global__ __launch_bounds__(1024) void bucket_scan(const int* __restrict__ bucketCount,
                                                    int* __restrict__ bucketOffset,
                                                    int* __restrict__ gCur,
                                                    int* __restrict__ rowPtrW) {
    __shared__ int s[1024];
    int t = threadIdx.x;
    int4 c = *(const int4*)(bucketCount + t * 4);
    int sum = c.x + c.y + c.z + c.w;
    s[t] = sum;
    __syncthreads();
    for (int off = 1; off < 1024; off <<= 1) {
        int x = (t >= off) ? s[t - off] : 0;
        __syncthreads();
        s[t] += x;
        __syncthreads();
    }
    int base = s[t] - sum;   // exclusive
    int i0 = t * 4;
    bucketOffset[i0]     = base;
    bucketOffset[i0 + 1] = base + c.x;
    bucketOffset[i0 + 2] = base + c.x + c.y;
    bucketOffset[i0 + 3] = base + c.x + c.y + c.z;
    gCur[i0]     = base;
    gCur[i0 + 1] = base + c.x;
    gCur[i0 + 2] = base + c.x + c.y;
    gCur[i0 + 3] = base + c.x + c.y + c.z;
    if (t == 0) {
        bucketOffset[NCNT] = N_EDGES;
        rowPtrW[N_NODES * NQ] = N_EDGES;
    }
}

// ---------- pass B: scatter packed edges into (bucket,part) runs ----------
// bpair u64: [norm14:32..45][src_local:9 @18][dst:18]
__global__ __launch_bounds__(BT) void bucket_scatter(const int* __restrict__ src,
                                                     const int* __restrict__ dst,
                                                     const float* __restrict__ norm,
                                                     int* __restrict__ gCur,
                                                     u64* __restrict__ bpair) {
    __shared__ int cnt[NBUCKET];
    __shared__ int bbase[NBUCKET];
    int t = threadIdx.x;
    int part = blockIdx.x & (NPART - 1);
    cnt[t] = 0;
    __syncthreads();
    int base = blockIdx.x * TILE + t;
    #pragma unroll
    for (int k = 0; k < VPT; ++k) {
        int e = base + k * BT;
        if (e < N_EDGES) atomicAdd(&cnt[src[e] / NPB], 1);
    }
    __syncthreads();
    int c = cnt[t];
    bbase[t] = c ? atomicAdd(&gCur[t * NPART + part], c) : 0;
    __syncthreads();
    cnt[t] = 0;
    __syncthreads();
    #pragma unroll
    for (int k = 0; k < VPT; ++k) {
        int e = base + k * BT;
        if (e < N_EDGES) {
            int s = src[e];
            int b = s / NPB;
            int sl = s - b * NPB;                    // 0..292
            int r = atomicAdd(&cnt[b], 1);
            uint nq = (uint)(norm[e] * NORM_SCALE + 0.5f);   // 14-bit fixed pt
            uint lo = (uint)dst[e] | ((uint)sl << 18);
            bpair[bbase[b] + r] = (u64)lo | ((u64)nq << 32);
        }
    }
}

// ---------- pass C: per-bucket counting sort by (src_local, dst>>15) --------
// Emits u32 pairs ([norm14 @18][dst:18]) + rowPtrW[node*NQ+w] extents.
__global__ __launch_bounds__(1024) void csr_finalize(const int* __restrict__ bucketOffset,
                                                     const u64* __restrict__ bpair,
                                                     int* __restrict__ rowPtrW,
                                                     uint* __restrict__ pairs) {
    __shared__ int cnt[NBIN2];      // 8 KB
    __shared__ int cur[NBIN2];      // 8 KB
    __shared__ int psum[1024];      // 4 KB
    int b = blockIdx.x;
    int t = threadIdx.x;            // 1024 threads
    int beg = bucketOffset[b * NPART];
    int end = bucketOffset[b * NPART + NPART];
    int nodeBase = b * NPB;

    cnt[t] = 0;
    cnt[t + 1024] = 0;
    __syncthreads();
    for (int i = beg + t; i < end; i += 1024) {
        uint lo = (uint)bpair[i];
        int sl = (lo >> 18) & 0x1FF;
        int q  = (lo & 0x3FFFF) >> 15;               // 0..4
        atomicAdd(&cnt[sl * NQ + q], 1);
    }
    __syncthreads();
    int c0 = cnt[2 * t];
    int c1 = cnt[2 * t + 1];
    int ps = c0 + c1;
    psum[t] = ps;
    __syncthreads();
    for (int off = 1; off < 1024; off <<= 1) {
        int x = (t >= off) ? psum[t - off] : 0;
        __syncthreads();
        psum[t] += x;
        __syncthreads();
    }
    int base = psum[t] - ps;        // exclusive over bin pairs
    cur[2 * t]     = base;
    cur[2 * t + 1] = base + c0;
    __syncthreads();
    for (int bin = t; bin < NBIN; bin += 1024) {
        int sl = bin / NQ;
        int q  = bin - sl * NQ;
        int node = nodeBase + sl;
        if (node < N_NODES) rowPtrW[node * NQ + q] = beg + cur[bin];
    }
    __syncthreads();
    for (int i = beg + t; i < end; i += 1024) {
        u64 p = bpair[i];
        uint lo = (uint)p;
        int sl = (lo >> 18) & 0x1FF;
        int q  = (lo & 0x3FFFF) >> 15;
        int r = atomicAdd(&cur[sl * NQ + q], 1);
        pairs[beg + r] = (lo & 0x3FFFF) | ((uint)(p >> 32) << 18);
    }
}

// ---------- cooperative windowed gather: all 3 layers, one kernel ----------
__global__ __launch_bounds__(256, 4) void lgcn_coop(
        const ushort* __restrict__ egoA,
        ushort* __restrict__ egoB,
        ushort* __restrict__ egoC,
        float* __restrict__ accOut,
        const int* __restrict__ rowPtrW,
        const uint* __restrict__ pairs) {
    cg::grid_group grid = cg::this_grid();
    int wid   = (int)((blockIdx.x * blockDim.x + threadIdx.x) >> 6);
    int lane  = (int)(threadIdx.x & 63);
    int nbase = wid * NPW;

    const __half* in = (const __half*)egoA;
    __half* out = (__half*)egoB;

    for (int layer = 0; layer < 3; ++layer) {
        float acc[NPW];
        #pragma unroll
        for (int s = 0; s < NPW; ++s) acc[s] = 0.f;

        for (int W = 0; W < NQ; ++W) {
            #pragma unroll
            for (int g = 0; g < NGRP; ++g) {
                int cu[8], en[8];
                #pragma unroll
                for (int j = 0; j < 8; ++j) {
                    int node = nbase + g * 8 + j;
                    if (node < N_NODES) {
                        cu[j] = rowPtrW[node * NQ + W];
                        en[j] = rowPtrW[node * NQ + W + 1];
                    } else { cu[j] = 0; en[j] = 0; }
                }
                int mx = 0;
                #pragma unroll
                for (int j = 0; j < 8; ++j) mx = max(mx, en[j] - cu[j]);
                for (int i = 0; i < mx; ++i) {
                    #pragma unroll
                    for (int j = 0; j < 8; ++j) {
                        if (cu[j] + i < en[j]) {
                            uint p = pairs[cu[j] + i];
                            float wgt = decw(p);
                            int d = (int)(p & 0x3FFFF);
                            acc[g * 8 + j] +=
                                wgt * __half2float(in[((size_t)d << 6) + lane]);
                        }
                    }
                }
            }
            if (W < NQ - 1) grid.sync();   // window pacing
        }

        if (layer < 2) {
            #pragma unroll
            for (int s = 0; s < NPW; ++s) {
                int node = nbase + s;
                if (node < N_NODES)
                    out[((size_t)node << 6) + lane] = __float2half(acc[s]);
            }
            __threadfence();               // cross-XCD visibility (G16)
            grid.sync();                   // layer boundary
        } else {
            const __half* hA = (const __half*)egoA;
            const __half* hB = (const __half*)egoB;
            const __half* hC = (const __half*)egoC;
            #pragma unroll
            for (int s = 0; s < NPW; ++s) {
                int node = nbase + s;
                if (node < N_NODES) {
                    size_t o = ((size_t)node << 6) + lane;
                    float r = __half2float(hA[o]) + __half2float(hB[o])
                            + __half2float(hC[o]) + acc[s];
                    accOut[o] = r * 0.25f;
                }
            }
        }
        in  = (const __half*)((layer == 0) ? egoB : egoC);
        out = (__half*)egoC;
    }
}

// ---------- fallback gather (verified round-13 structure, u32 pairs) --------
// finalMode==0: nego = fp16(s);  finalMode==1: acc = (e0+e1+ego+s)*0.25
__global__ void lgcn_gather(const ushort* __restrict__ ego,
                            ushort* __restrict__ nego,
                            float* __restrict__ acc,
                            const ushort* __restrict__ e0,
                            const ushort* __restrict__ e1,
                            const int* __restrict__ rowPtrW,
                            const uint* __restrict__ pairs,
                            int finalMode) {
    int node   = blockIdx.x * 8 + (threadIdx.x >> 5);
    int lane32 = threadIdx.x & 31;
    int g      = lane32 >> 3;
    int sub    = lane32 & 7;
    if (node >= N_NODES) return;
    int beg = rowPtrW[node * NQ];
    int end = rowPtrW[node * NQ + NQ];

    float a0 = 0.f, a1 = 0.f, a2 = 0.f, a3 = 0.f;
    float a4 = 0.f, a5 = 0.f, a6 = 0.f, a7 = 0.f;
    float b0 = 0.f, b1 = 0.f, b2 = 0.f, b3 = 0.f;
    float b4 = 0.f, b5 = 0.f, b6 = 0.f, b7 = 0.f;

    int i = beg + g;
    for (; i + 4 < end; i += 8) {
        uint pA = pairs[i];
        uint pB = pairs[i + 4];
        float wA = decw(pA);
        float wB = decw(pB);
        uint4 rA = *(const uint4*)(ego + ((size_t)(pA & 0x3FFFF) << 6) + (sub << 3));
        uint4 rB = *(const uint4*)(ego + ((size_t)(pB & 0x3FFFF) << 6) + (sub << 3));
        float2 q;
        q = h2f2(rA.x); a0 += wA * q.x; a1 += wA * q.y;
        q = h2f2(rA.y); a2 += wA * q.x; a3 += wA * q.y;
        q = h2f2(rA.z); a4 += wA * q.x; a5 += wA * q.y;
        q = h2f2(rA.w); a6 += wA * q.x; a7 += wA * q.y;
        q = h2f2(rB.x); b0 += wB * q.x; b1 += wB * q.y;
        q = h2f2(rB.y); b2 += wB * q.x; b3 += wB * q.y;
        q = h2f2(rB.z); b4 += wB * q.x; b5 += wB * q.y;
        q = h2f2(rB.w); b6 += wB * q.x; b7 += wB * q.y;
    }
    if (i < end) {
        uint p = pairs[i];
        float w = decw(p);
        uint4 r = *(const uint4*)(ego + ((size_t)(p & 0x3FFFF) << 6) + (sub << 3));
        float2 q;
        q = h2f2(r.x); a0 += w * q.x; a1 += w * q.y;
        q = h2f2(r.y); a2 += w * q.x; a3 += w * q.y;
        q = h2f2(r.z); a4 += w * q.x; a5 += w * q.y;
        q = h2f2(r.w); a6 += w * q.x; a7 += w * q.y;
    }
    float s0 = a0 + b0, s1 = a1 + b1, s2 = a2 + b2, s3 = a3 + b3;
    float s4 = a4 + b4, s5 = a5 + b5, s6 = a6 + b6, s7 = a7 + b7;

    s0 += __shfl_down(s0, 16); s1 += __shfl_down(s1, 16);
    s2 += __shfl_down(s2, 16); s3 += __shfl_down(s3, 16);
    s4 += __shfl_down(s4, 16); s5 += __shfl_down(s5, 16);
    s6 += __shfl_down(s6, 16); s7 += __shfl_down(s7, 16);
    s0 += __shfl_down(s0, 8);  s1 += __shfl_down(s1, 8);
    s2 += __shfl_down(s2, 8);  s3 += __shfl_down(s3, 8);
    s4 += __shfl_down(s4, 8);  s5 += __shfl_down(s5, 8);
    s6 += __shfl_down(s6, 8);  s7 += __shfl_down(s7, 8);

    if (lane32 < 8) {
        size_t ro = ((size_t)node << 6) + (lane32 << 3);
        if (!finalMode) {
            uint4* np = (uint4*)(nego + ro);
            *np = make_uint4(f2h2(s0, s1), f2h2(s2, s3),
                             f2h2(s4, s5), f2h2(s6, s7));
        } else {
            uint4 z0 = *(const uint4*)(e0  + ro);
            uint4 z1 = *(const uint4*)(e1  + ro);
            uint4 z2 = *(const uint4*)(ego + ro);
            float2 a, b, c;
            float4 o0, o1;
            a = h2f2(z0.x); b = h2f2(z1.x); c = h2f2(z2.x);
            o0.x = (a.x + b.x + c.x + s0) * 0.25f;
            o0.y = (a.y + b.y + c.y + s1) * 0.25f;
            a = h2f2(z0.y); b = h2f2(z1.y); c = h2f2(z2.y);
            o0.z = (a.x + b.x + c.x + s2) * 0.25f;
            o0.w = (a.y + b.y + c.y + s3) * 0.25f;
            a = h2f2(z0.z); b = h2f2(z1.z); c = h2f2(z2.z);
            o1.x = (a.x + b.x + c.x + s4) * 0.25f;
            o1.y = (a.y + b.y + c.y + s5) * 0.25f;
            a = h2f2(z0.w); b = h2f2(z1.w); c = h2f2(z2.w);
            o1.z = (a.x + b.x + c.x + s6) * 0.25f;
            o1.w = (a.y + b.y + c.y + s7) * 0.25f;
            float4* ap = (float4*)(acc + ro);
            ap[0] = o0;
            ap[1] = o1;
        }
    }
}

extern "C" void kernel_launch(void* const* d_in, const int* in_sizes, int n_in,
                              void* d_out, int out_size, void* d_ws, size_t ws_size,
                              hipStream_t stream) {
    const float* user_emb  = (const float*)d_in[0];
    const float* item_emb  = (const float*)d_in[1];
    const float* edge_norm = (const float*)d_in[2];
    const int*   edge_src  = (const int*)d_in[3];
    const int*   edge_dst  = (const int*)d_in[4];
    float* acc = (float*)d_out;

    char* w = (char*)d_ws;
    ushort* egoA  = (ushort*)w;                      w += (size_t)NODE_FLOATS * 2;   // 19.2 MB
    ushort* egoB  = (ushort*)w;                      w += (size_t)NODE_FLOATS * 2;   // 19.2 MB
    uint*  pairs  = (uint*)w;                        w += (size_t)N_EDGES * 4;       // 8 MB
    int*   rowPtrW = (int*)w;                        w += (size_t)(N_NODES * NQ + 8) * 4; // 3 MB
    int*   bucketCount  = (int*)w;                   w += (size_t)NCNT * 4;
    int*   bucketOffset = (int*)w;                   w += (size_t)(NCNT + 4) * 4;
    int*   gCur   = (int*)w;                         w += (size_t)NCNT * 4;
    // bpair (16 MB, dead after csr_finalize) and egoC (19.2 MB, born at the
    // layer-1 epilogue) share the tail. Total footprint ~68.7 MB.
    u64*   bpair  = (u64*)w;
    ushort* egoC  = (ushort*)w;

    const int T = 256;
    const int GATHER_BLOCKS = (N_NODES + 7) / 8;     // 18750

    hipMemsetAsync(bucketCount, 0, (size_t)NCNT * 4, stream);
    init_and_hist<<<NTILE + INITB, BT, 0, stream>>>(
        (const float4*)user_emb, (const float4*)item_emb, (uint2*)egoA,
        edge_src, bucketCount);
    bucket_scan<<<1, 1024, 0, stream>>>(bucketCount, bucketOffset, gCur, rowPtrW);
    bucket_scatter<<<NTILE, BT, 0, stream>>>(edge_src, edge_dst, edge_norm,
                                             gCur, bpair);
    csr_finalize<<<NBUCKET, 1024, 0, stream>>>(bucketOffset, bpair,
                                               rowPtrW, pairs);

    void* cargs[] = { (void*)&egoA, (void*)&egoB, (void*)&egoC,
                      (void*)&acc, (void*)&rowPtrW, (void*)&pairs };
    hipError_t cerr = hipLaunchCooperativeKernel((void*)lgcn_coop,
                                                 dim3(COOP_BLOCKS), dim3(256),
                                                 cargs, 0, stream);
    if (cerr != hipSuccess) {
        (void)hipGetLastError();   // clear sticky error, take fallback path
        lgcn_gather<<<GATHER_BLOCKS, T, 0, stream>>>(egoA, egoB, acc,
                                                     (const ushort*)0,
                                                     (const ushort*)0,
                                                     rowPtrW, pairs, 0);
        lgcn_gather<<<GATHER_BLOCKS, T, 0, stream>>>(egoB, egoC, acc,
                                                     (const ushort*)0,
                                                     (const ushort*)0,
                                                     rowPtrW, pairs, 0);
        lgcn_gather<<<GATHER_BLOCKS, T, 0, stream>>>(egoC, (ushort*)0, acc,
                                                     egoA, egoB,
                                                     rowPtrW, pairs, 1);
    }
}

// Round 13
// 324.732 us; speedup vs baseline: 10.3369x; 10.3369x over previous
//
#include <hip/hip_runtime.h>
#include <hip/hip_fp16.h>

// LightGCN 3-layer propagation, pull-based CSR, fp16 ego intermediates.
// Round 19: pre-committed revert. The cooperative window-sweep (round 18)
// ran at 3181us — acc[40]/thread spilled to scratch (WRITE_SIZE 251MB vs
// 29MB algorithmic; VALU 5%) + 14 grid syncs. Window-sync line CLOSED.
// Base = verified round-16 (329.0us). One retained improvement from the
// r18 prep: u32 pairs ([norm 14-bit fixed pt @18][dst:18], quant err
// <=6e-5 vs 0.405 tolerance) — halves pairs traffic in all 3 gathers and
// halves csr_finalize's output write.

#define NUM_USERS 100000
#define NUM_ITEMS 50000
#define EMB_DIM   64
#define N_EDGES   2000000
#define N_NODES   (NUM_USERS + NUM_ITEMS)          // 150000
#define NODE_FLOATS (N_NODES * EMB_DIM)            // 9,600,000
#define NODE_F4     (NODE_FLOATS / 4)              // 2,400,000

#define NBUCKET  512
#define NPB      293        // nodes per bucket; 512*293 = 150016 >= 150000
#define NPART    8          // reservation partitions (XCD heuristic)
#define NCNT     (NBUCKET * NPART)                  // 4096
#define BT       512        // threads in bucket passes
#define VPT      8          // edges per thread in bucket passes
#define TILE     (BT * VPT)                         // 4096
#define NTILE    ((N_EDGES + TILE - 1) / TILE)      // 489
#define INITB    1024       // init-role blocks in the fused kernel

#define NORM_SCALE 16383.0f

typedef unsigned int uint;
typedef unsigned short ushort;
typedef unsigned long long u64;

__device__ __forceinline__ float2 h2f2(uint u) {
    __half2 h = *reinterpret_cast<const __half2*>(&u);
    return __half22float2(h);
}
__device__ __forceinline__ uint f2h2(float a, float b) {
    __half2 h = __floats2half2_rn(a, b);
    return *reinterpret_cast<uint*>(&h);
}
__device__ __forceinline__ float decw(uint p) {
    return (float)(p >> 18) * (1.0f / NORM_SCALE);
}

// ---------- fused: egoA(fp16) = concat(user,item)  +  bucket histogram ----
__global__ __launch_bounds__(BT) void init_and_hist(
        const float4* __restrict__ user,
        const float4* __restrict__ item,
        uint2* __restrict__ egoA,
        const int* __restrict__ src,
        int* __restrict__ bucketCount) {
    int t = threadIdx.x;
    if (blockIdx.x < NTILE) {
        __shared__ int cnt[NBUCKET];
        int part = blockIdx.x & (NPART - 1);
        cnt[t] = 0;
        __syncthreads();
        int base = blockIdx.x * TILE + t;
        #pragma unroll
        for (int k = 0; k < VPT; ++k) {
            int e = base + k * BT;
            if (e < N_EDGES) atomicAdd(&cnt[src[e] / NPB], 1);
        }
        __syncthreads();
        int c = cnt[t];
        if (c) atomicAdd(&bucketCount[t * NPART + part], c);
    } else {
        const int n_user4 = NUM_USERS * EMB_DIM / 4;
        int bid = blockIdx.x - NTILE;
        for (int i = bid * BT + t; i < NODE_F4; i += INITB * BT) {
            float4 v = (i < n_user4) ? user[i] : item[i - n_user4];
            egoA[i] = make_uint2(f2h2(v.x, v.y), f2h2(v.z, v.w));
        }
    }
}

// ---------- scan over 4096 (bucket,part) counters (1 block, 1024 thr) ----------
__global__ __launch_bounds__(1024) void bucket_scan(const int* __restrict__ bucketCount,
                                                    int* __restrict__ bucketOffset,
                                                    int* __restrict__ gCur,
                                                    int* __restrict__ rowPtr) {
    __shared__ int s[1024];
    int t = threadIdx.x;
    int4 c = *(const int4*)(bucketCount + t * 4);
    int sum = c.x + c.y + c.z + c.w;
    s[t] = sum;
    __syncthreads();
    for (int off = 1; off < 1024; off <<= 1) {
        int x = (t >= off) ? s[t - off] : 0;
        __syncthreads();
        s[t] += x;
        __syncthreads();
    }
    int base = s[t] - sum;   // exclusive
    int i0 = t * 4;
    bucketOffset[i0]     = base;
    bucketOffset[i0 + 1] = base + c.x;
    bucketOffset[i0 + 2] = base + c.x + c.y;
    bucketOffset[i0 + 3] = base + c.x + c.y + c.z;
    gCur[i0]     = base;
    gCur[i0 + 1] = base + c.x;
    gCur[i0 + 2] = base + c.x + c.y;
    gCur[i0 + 3] = base + c.x + c.y + c.z;
    if (t == 0) {
        bucketOffset[NCNT] = N_EDGES;
        rowPtr[N_NODES] = N_EDGES;
    }
}

// ---------- pass B: scatter packed edges into (bucket,part) runs ----------
// bpair u64: [norm14 @32][src_local:9 @18][dst:18]
__global__ __launch_bounds__(BT) void bucket_scatter(const int* __restrict__ src,
                                                     const int* __restrict__ dst,
                                                     const float* __restrict__ norm,
                                                     int* __restrict__ gCur,
                                                     u64* __restrict__ bpair) {
    __shared__ int cnt[NBUCKET];
    __shared__ int bbase[NBUCKET];
    int t = threadIdx.x;
    int part = blockIdx.x & (NPART - 1);
    cnt[t] = 0;
    __syncthreads();
    int base = blockIdx.x * TILE + t;
    #pragma unroll
    for (int k = 0; k < VPT; ++k) {
        int e = base + k * BT;
        if (e < N_EDGES) atomicAdd(&cnt[src[e] / NPB], 1);
    }
    __syncthreads();
    int c = cnt[t];
    bbase[t] = c ? atomicAdd(&gCur[t * NPART + part], c) : 0;
    __syncthreads();
    cnt[t] = 0;
    __syncthreads();
    #pragma unroll
    for (int k = 0; k < VPT; ++k) {
        int e = base + k * BT;
        if (e < N_EDGES) {
            int s = src[e];
            int b = s / NPB;
            int sl = s - b * NPB;                    // 0..292
            int r = atomicAdd(&cnt[b], 1);
            uint nq = (uint)(norm[e] * NORM_SCALE + 0.5f);   // 14-bit fixed pt
            uint lo = (uint)dst[e] | ((uint)sl << 18);
            bpair[bbase[b] + r] = (u64)lo | ((u64)nq << 32);
        }
    }
}

// ---------- pass C: per-bucket CSR finalize (counting sort by src_local) ----
// Emits u32 pairs: [norm14 @18][dst:18].
__global__ __launch_bounds__(1024) void csr_finalize(const int* __restrict__ bucketOffset,
                                                     const u64* __restrict__ bpair,
                                                     int* __restrict__ rowPtr,
                                                     uint* __restrict__ pairs) {
    __shared__ int cnt[NBUCKET];
    __shared__ int cur[NBUCKET];
    int b = blockIdx.x;
    int t = threadIdx.x;          // 1024 threads
    int beg = bucketOffset[b * NPART];
    int end = bucketOffset[b * NPART + NPART];
    int nodeBase = b * NPB;

    if (t < NBUCKET) cnt[t] = 0;
    __syncthreads();
    for (int i = beg + t; i < end; i += 1024) {
        uint lo = (uint)bpair[i];
        atomicAdd(&cnt[(lo >> 18) & 0x1FF], 1);
    }
    __syncthreads();
    int v = (t < NBUCKET) ? cnt[t] : 0;
    for (int off = 1; off < NBUCKET; off <<= 1) {     // inclusive scan, 512-wide
        int x = (t >= off && t < NBUCKET) ? cnt[t - off] : 0;
        __syncthreads();
        if (t < NBUCKET) cnt[t] += x;
        __syncthreads();
    }
    if (t < NBUCKET) {
        int excl = cnt[t] - v;
        cur[t] = excl;
        int node = nodeBase + t;
        if (t < NPB && node < N_NODES) rowPtr[node] = beg + excl;
    }
    __syncthreads();
    for (int i = beg + t; i < end; i += 1024) {
        u64 p = bpair[i];
        uint lo = (uint)p;
        int s = (lo >> 18) & 0x1FF;
        int r = atomicAdd(&cur[s], 1);
        pairs[beg + r] = (lo & 0x3FFFF) | ((uint)(p >> 32) << 18);
    }
}

// ---------- gather: 2 nodes/wave, 4 streams x 2-deep unroll per node ----------
// (verified round-13 structure; pairs are u32 [norm14@18][dst:18])
// finalMode==0: nego = fp16(s)                    (no acc access)
// finalMode==1: acc  = (e0 + e1 + ego + s) * 0.25 (no nego write)
__global__ void lgcn_gather(const ushort* __restrict__ ego,
                            ushort* __restrict__ nego,
                            float* __restrict__ acc,
                            const ushort* __restrict__ e0,
                            const ushort* __restrict__ e1,
                            const int* __restrict__ rowPtr,
                            const uint* __restrict__ pairs,
                            int finalMode) {
    // 256 threads = 4 waves = 8 nodes (one node per 32-lane half-wave)
    int node   = blockIdx.x * 8 + (threadIdx.x >> 5);
    int lane32 = threadIdx.x & 31;
    int g      = lane32 >> 3;       // 4 edge streams per node
    int sub    = lane32 & 7;        // uint4 position within the 128B row
    if (node >= N_NODES) return;
    int beg = rowPtr[node];
    int end = rowPtr[node + 1];

    float a0 = 0.f, a1 = 0.f, a2 = 0.f, a3 = 0.f;
    float a4 = 0.f, a5 = 0.f, a6 = 0.f, a7 = 0.f;
    float b0 = 0.f, b1 = 0.f, b2 = 0.f, b3 = 0.f;
    float b4 = 0.f, b5 = 0.f, b6 = 0.f, b7 = 0.f;

    int i = beg + g;
    for (; i + 4 < end; i += 8) {
        uint pA = pairs[i];
        uint pB = pairs[i + 4];
        float wA = decw(pA);
        float wB = decw(pB);
        uint4 rA = *(const uint4*)(ego + ((size_t)(pA & 0x3FFFF) << 6) + (sub << 3));
        uint4 rB = *(const uint4*)(ego + ((size_t)(pB & 0x3FFFF) << 6) + (sub << 3));
        float2 q;
        q = h2f2(rA.x); a0 += wA * q.x; a1 += wA * q.y;
        q = h2f2(rA.y); a2 += wA * q.x; a3 += wA * q.y;
        q = h2f2(rA.z); a4 += wA * q.x; a5 += wA * q.y;
        q = h2f2(rA.w); a6 += wA * q.x; a7 += wA * q.y;
        q = h2f2(rB.x); b0 += wB * q.x; b1 += wB * q.y;
        q = h2f2(rB.y); b2 += wB * q.x; b3 += wB * q.y;
        q = h2f2(rB.z); b4 += wB * q.x; b5 += wB * q.y;
        q = h2f2(rB.w); b6 += wB * q.x; b7 += wB * q.y;
    }
    if (i < end) {
        uint p = pairs[i];
        float w = decw(p);
        uint4 r = *(const uint4*)(ego + ((size_t)(p & 0x3FFFF) << 6) + (sub << 3));
        float2 q;
        q = h2f2(r.x); a0 += w * q.x; a1 += w * q.y;
        q = h2f2(r.y); a2 += w * q.x; a3 += w * q.y;
        q = h2f2(r.z); a4 += w * q.x; a5 += w * q.y;
        q = h2f2(r.w); a6 += w * q.x; a7 += w * q.y;
    }
    float s0 = a0 + b0, s1 = a1 + b1, s2 = a2 + b2, s3 = a3 + b3;
    float s4 = a4 + b4, s5 = a5 + b5, s6 = a6 + b6, s7 = a7 + b7;

    // reduce 4 streams -> lanes (lane32 < 8) of each half-wave.
    s0 += __shfl_down(s0, 16); s1 += __shfl_down(s1, 16);
    s2 += __shfl_down(s2, 16); s3 += __shfl_down(s3, 16);
    s4 += __shfl_down(s4, 16); s5 += __shfl_down(s5, 16);
    s6 += __shfl_down(s6, 16); s7 += __shfl_down(s7, 16);
    s0 += __shfl_down(s0, 8);  s1 += __shfl_down(s1, 8);
    s2 += __shfl_down(s2, 8);  s3 += __shfl_down(s3, 8);
    s4 += __shfl_down(s4, 8);  s5 += __shfl_down(s5, 8);
    s6 += __shfl_down(s6, 8);  s7 += __shfl_down(s7, 8);

    if (lane32 < 8) {
        size_t ro = ((size_t)node << 6) + (lane32 << 3);   // dims lane32*8..+7
        if (!finalMode) {
            uint4* np = (uint4*)(nego + ro);
            *np = make_uint4(f2h2(s0, s1), f2h2(s2, s3),
                             f2h2(s4, s5), f2h2(s6, s7));
        } else {
            uint4 z0 = *(const uint4*)(e0  + ro);
            uint4 z1 = *(const uint4*)(e1  + ro);
            uint4 z2 = *(const uint4*)(ego + ro);
            float2 a, b, c;
            float4 o0, o1;
            a = h2f2(z0.x); b = h2f2(z1.x); c = h2f2(z2.x);
            o0.x = (a.x + b.x + c.x + s0) * 0.25f;
            o0.y = (a.y + b.y + c.y + s1) * 0.25f;
            a = h2f2(z0.y); b = h2f2(z1.y); c = h2f2(z2.y);
            o0.z = (a.x + b.x + c.x + s2) * 0.25f;
            o0.w = (a.y + b.y + c.y + s3) * 0.25f;
            a = h2f2(z0.z); b = h2f2(z1.z); c = h2f2(z2.z);
            o1.x = (a.x + b.x + c.x + s4) * 0.25f;
            o1.y = (a.y + b.y + c.y + s5) * 0.25f;
            a = h2f2(z0.w); b = h2f2(z1.w); c = h2f2(z2.w);
            o1.z = (a.x + b.x + c.x + s6) * 0.25f;
            o1.w = (a.y + b.y + c.y + s7) * 0.25f;
            float4* ap = (float4*)(acc + ro);
            ap[0] = o0;
            ap[1] = o1;
        }
    }
}

extern "C" void kernel_launch(void* const* d_in, const int* in_sizes, int n_in,
                              void* d_out, int out_size, void* d_ws, size_t ws_size,
                              hipStream_t stream) {
    const float* user_emb  = (const float*)d_in[0];
    const float* item_emb  = (const float*)d_in[1];
    const float* edge_norm = (const float*)d_in[2];
    const int*   edge_src  = (const int*)d_in[3];
    const int*   edge_dst  = (const int*)d_in[4];
    float* acc = (float*)d_out;

    char* w = (char*)d_ws;
    ushort* egoA  = (ushort*)w;                      w += (size_t)NODE_FLOATS * 2;   // 19.2 MB
    ushort* egoB  = (ushort*)w;                      w += (size_t)NODE_FLOATS * 2;   // 19.2 MB
    uint*  pairs  = (uint*)w;                        w += (size_t)N_EDGES * 4;       // 8 MB
    int*   rowPtr = (int*)w;                         w += (size_t)(N_NODES + 4) * 4;
    int*   bucketCount  = (int*)w;                   w += (size_t)NCNT * 4;
    int*   bucketOffset = (int*)w;                   w += (size_t)(NCNT + 4) * 4;
    int*   gCur   = (int*)w;                         w += (size_t)NCNT * 4;
    // bpair (16 MB, dead after csr_finalize) and egoC (19.2 MB, born at
    // layer-2 gather) share the tail region: lifetimes don't overlap.
    u64*   bpair  = (u64*)w;
    ushort* egoC  = (ushort*)w;

    const int T = 256;
    const int GATHER_BLOCKS = (N_NODES + 7) / 8;     // 18750

    hipMemsetAsync(bucketCount, 0, (size_t)NCNT * 4, stream);
    init_and_hist<<<NTILE + INITB, BT, 0, stream>>>(
        (const float4*)user_emb, (const float4*)item_emb, (uint2*)egoA,
        edge_src, bucketCount);
    bucket_scan<<<1, 1024, 0, stream>>>(bucketCount, bucketOffset, gCur, rowPtr);
    bucket_scatter<<<NTILE, BT, 0, stream>>>(edge_src, edge_dst, edge_norm,
                                             gCur, bpair);
    csr_finalize<<<NBUCKET, 1024, 0, stream>>>(bucketOffset, bpair,
                                               rowPtr, pairs);

    // Layer 1: ego0(A) -> ego1(B)             (nego only)
    lgcn_gather<<<GATHER_BLOCKS, T, 0, stream>>>(egoA, egoB, acc,
                                                 (const ushort*)0, (const ushort*)0,
                                                 rowPtr, pairs, 0);
    // Layer 2: ego1(B) -> ego2(C)             (nego only)
    lgcn_gather<<<GATHER_BLOCKS, T, 0, stream>>>(egoB, egoC, acc,
                                                 (const ushort*)0, (const ushort*)0,
                                                 rowPtr, pairs, 0);
    // Layer 3: ego2(C) -> s; acc = (A + B + C + s) / 4
    lgcn_gather<<<GATHER_BLOCKS, T, 0, stream>>>(egoC, (ushort*)0, acc,
                                                 egoA, egoB,
                                                 rowPtr, pairs, 1);
}